// Round 4
// baseline (420.934 us; speedup 1.0000x reference)
//
#include <hip/hip_runtime.h>
#include <hip/hip_bf16.h>

// CrossAttention with KV length 1: softmax over size-1 axis == 1, so Q/K are
// dead. out[b,n,:] = (freq[b] @ Wv.T + bv) @ Wo.T + bo, broadcast over n.
//
// Structure: tiny compute kernel (16 blocks) producing O2[16,768] into d_ws,
// then a max-occupancy streaming broadcast kernel: 2048 blocks x 256 threads
// (8 blocks/CU -> 32 waves/CU), each block sweeping a contiguous 96 KB chunk
// with nontemporal float4 stores, values held in registers.

#define B_    16
#define N_    4096
#define CSP   768
#define CFD   512

typedef float vfloat4 __attribute__((ext_vector_type(4)));  // native vec for nt-store

// ---------------- Kernel 1: O2[b,c] for all b ----------------
// grid 16 (one block per batch), 768 threads (one output element per thread)
__global__ void __launch_bounds__(768) compute_o2_all(
    const float* __restrict__ freq,   // [B, CFD]
    const float* __restrict__ Wv,     // [CSP, CFD]
    const float* __restrict__ bv,     // [CSP]
    const float* __restrict__ Wo,     // [CSP, CSP]
    const float* __restrict__ bo,     // [CSP]
    float* __restrict__ O2)           // [B, CSP] in d_ws
{
    const int b = blockIdx.x;
    const int t = threadIdx.x;

    __shared__ __align__(16) float sF[CFD];
    __shared__ __align__(16) float sV[CSP];

    if (t < CFD) sF[t] = freq[(size_t)b * CFD + t];
    __syncthreads();

    // V[t] = bv[t] + dot(freq[b], Wv[t,:])
    {
        float acc = bv[t];
        const float4* wr = (const float4*)Wv + (size_t)t * (CFD / 4);
        const float4* fr = (const float4*)sF;
#pragma unroll 8
        for (int i = 0; i < CFD / 4; ++i) {
            float4 w = wr[i];
            float4 f = fr[i];
            acc += w.x * f.x + w.y * f.y + w.z * f.z + w.w * f.w;
        }
        sV[t] = acc;
    }
    __syncthreads();

    // O2[t] = bo[t] + dot(V, Wo[t,:])
    {
        float acc = bo[t];
        const float4* wr = (const float4*)Wo + (size_t)t * (CSP / 4);
        const float4* vr = (const float4*)sV;
#pragma unroll 8
        for (int i = 0; i < CSP / 4; ++i) {
            float4 w = wr[i];
            float4 v = vr[i];
            acc += w.x * v.x + w.y * v.y + w.z * v.z + w.w * v.w;
        }
        O2[(size_t)b * CSP + t] = acc;
    }
}

// ---------------- Kernel 2: streaming broadcast ----------------
// grid (16, 128) = 2048 blocks, 256 threads (4 waves). Block (b,y) writes
// rows [32y, 32y+32) of batch b = 96 KB contiguous, as 24 iterations of
// 4 KB (256 threads x float4) with monotonically increasing addresses.
// Column pattern per thread has period 3: col4(i) = (t + 64*i) mod 192,
// so each thread pre-loads its 3 O2 float4s into registers once.
__global__ void __launch_bounds__(256) broadcast_out(
    const float* __restrict__ O2,     // [B, CSP]
    float* __restrict__ out)          // [B, N, CSP]
{
    const int b = blockIdx.x;
    const int y = blockIdx.y;
    const int t = threadIdx.x;

    const vfloat4* row = (const vfloat4*)(O2 + (size_t)b * CSP);
    vfloat4 v[3];
#pragma unroll
    for (int j = 0; j < 3; ++j) {
        int c = t + 64 * j;            // < 384
        if (c >= 192) c -= 192;
        v[j] = row[c];
    }

    vfloat4* dst = (vfloat4*)(out + ((size_t)b * N_ + (size_t)y * 32) * CSP) + t;
#pragma unroll
    for (int i = 0; i < 24; ++i) {
        __builtin_nontemporal_store(v[i % 3], dst + (size_t)i * 256);
    }
}

extern "C" void kernel_launch(void* const* d_in, const int* in_sizes, int n_in,
                              void* d_out, int out_size, void* d_ws, size_t ws_size,
                              hipStream_t stream) {
    // Inputs (setup_inputs order):
    // 0: spatial_tokens (dead)  1: freq_token [B,CFD]
    // 2: Wq (dead) 3: bq (dead) 4: Wk (dead) 5: bk (dead)
    // 6: Wv [CSP,CFD] 7: bv [CSP] 8: Wo [CSP,CSP] 9: bo [CSP]
    const float* freq = (const float*)d_in[1];
    const float* Wv   = (const float*)d_in[6];
    const float* bv   = (const float*)d_in[7];
    const float* Wo   = (const float*)d_in[8];
    const float* bo   = (const float*)d_in[9];
    float* out = (float*)d_out;

    float* O2 = (float*)d_ws;   // [B, CSP] = 48 KB scratch

    compute_o2_all<<<dim3(B_), 768, 0, stream>>>(freq, Wv, bv, Wo, bo, O2);
    broadcast_out<<<dim3(B_, N_ / 32), 256, 0, stream>>>(O2, out);
}

// Round 5
// 346.396 us; speedup vs baseline: 1.2152x; 1.2152x over previous
//
#include <hip/hip_runtime.h>
#include <hip/hip_bf16.h>

// CrossAttention with KV length 1: softmax over size-1 axis == 1, so Q/K are
// dead. out[b,n,:] = (freq[b] @ Wv.T + bv) @ Wo.T + bo, broadcast over n.
//
// Round 5 structure = round 1 (best measured, 348.8 us total) with ONE change:
// the broadcast kernel. Compute kernels keep 96 blocks each (latency hidden by
// TLP; the 16-block fused variant of R4 was latency-bound). Broadcast uses
// 256 threads, O2 values held in 3 registers (period-3 column pattern),
// REGULAR float4 stores (nt-store was not faster), linear block->address map.

#define B_   16
#define N_   4096
#define CSP  768
#define CFD  512

// Kernel 1: V[b,j] = bv[j] + dot(freq[b,:], Wv[j,:])   (V: [B, CSP])
// grid (B, 6), block 128 -> j = by*128 + tid covers 768
__global__ void __launch_bounds__(128) compute_v(const float* __restrict__ freq,
                                                 const float* __restrict__ Wv,
                                                 const float* __restrict__ bv,
                                                 float* __restrict__ V) {
    const int b   = blockIdx.x;
    const int tid = threadIdx.x;
    const int j   = blockIdx.y * 128 + tid;

    __shared__ float4 sF[CFD / 4];                      // 512 floats = 128 float4
    sF[tid] = ((const float4*)(freq + (size_t)b * CFD))[tid];
    __syncthreads();

    float acc = bv[j];
    const float4* wr = (const float4*)Wv + (size_t)j * (CFD / 4);
#pragma unroll 4
    for (int i = 0; i < CFD / 4; ++i) {
        float4 w = wr[i];
        float4 f = sF[i];
        acc += w.x * f.x + w.y * f.y + w.z * f.z + w.w * f.w;
    }
    V[(size_t)b * CSP + j] = acc;
}

// Kernel 2: O2[b,c] = bo[c] + dot(V[b,:], Wo[c,:])     (O2: [B, CSP])
// grid (B, 6), block 128 -> c = by*128 + tid covers 768
__global__ void __launch_bounds__(128) compute_o2(const float* __restrict__ V,
                                                  const float* __restrict__ Wo,
                                                  const float* __restrict__ bo,
                                                  float* __restrict__ O2) {
    const int b   = blockIdx.x;
    const int tid = threadIdx.x;
    const int c   = blockIdx.y * 128 + tid;

    __shared__ float4 sV[CSP / 4];                      // 768 floats = 192 float4
    for (int i = tid; i < CSP / 4; i += 128)
        sV[i] = ((const float4*)(V + (size_t)b * CSP))[i];
    __syncthreads();

    float acc = bo[c];
    const float4* wr = (const float4*)Wo + (size_t)c * (CSP / 4);
#pragma unroll 4
    for (int i = 0; i < CSP / 4; ++i) {
        float4 w = wr[i];
        float4 v = sV[i];
        acc += w.x * v.x + w.y * v.y + w.z * v.z + w.w * v.w;
    }
    O2[(size_t)b * CSP + c] = acc;
}

// Kernel 3: streaming broadcast, out[b,n,:] = O2[b,:].
// 1-D grid of 2048 blocks x 256 threads; block k writes the k-th contiguous
// 96 KB chunk (32 rows) -> consecutive blocks write consecutive addresses,
// like the harness fill. Each of the 24 iterations stores a contiguous 4 KB
// slab (256 threads x float4). Column pattern per thread has period 3:
// col4(i) = (t + 64*i) mod 192, so 3 pre-loaded registers cover all stores.
__global__ void __launch_bounds__(256) broadcast_out(
    const float* __restrict__ O2,     // [B, CSP]
    float* __restrict__ out)          // [B, N, CSP]
{
    const int blk = blockIdx.x;       // 0..2047
    const int b   = blk >> 7;         // 128 chunks per batch
    const int y   = blk & 127;
    const int t   = threadIdx.x;

    const float4* row = (const float4*)(O2 + (size_t)b * CSP);
    float4 v[3];
#pragma unroll
    for (int j = 0; j < 3; ++j) {
        int c = t + 64 * j;            // < 384
        if (c >= 192) c -= 192;
        v[j] = row[c];
    }

    float4* dst = (float4*)(out + ((size_t)b * N_ + (size_t)y * 32) * CSP) + t;
#pragma unroll
    for (int i = 0; i < 24; ++i) {
        dst[(size_t)i * 256] = v[i % 3];
    }
}

extern "C" void kernel_launch(void* const* d_in, const int* in_sizes, int n_in,
                              void* d_out, int out_size, void* d_ws, size_t ws_size,
                              hipStream_t stream) {
    // Inputs (setup_inputs order):
    // 0: spatial_tokens (dead)  1: freq_token [B,CFD]
    // 2: Wq (dead) 3: bq (dead) 4: Wk (dead) 5: bk (dead)
    // 6: Wv [CSP,CFD] 7: bv [CSP] 8: Wo [CSP,CSP] 9: bo [CSP]
    const float* freq = (const float*)d_in[1];
    const float* Wv   = (const float*)d_in[6];
    const float* bv   = (const float*)d_in[7];
    const float* Wo   = (const float*)d_in[8];
    const float* bo   = (const float*)d_in[9];
    float* out = (float*)d_out;

    float* V  = (float*)d_ws;            // [B, CSP]
    float* O2 = V + (size_t)B_ * CSP;    // [B, CSP]

    compute_v <<<dim3(B_, CSP / 128), 128, 0, stream>>>(freq, Wv, bv, V);
    compute_o2<<<dim3(B_, CSP / 128), 128, 0, stream>>>(V, Wo, bo, O2);
    broadcast_out<<<dim3(2048), 256, 0, stream>>>(O2, out);
}

// Round 6
// 317.442 us; speedup vs baseline: 1.3260x; 1.0912x over previous
//
#include <hip/hip_runtime.h>
#include <hip/hip_bf16.h>

// CrossAttention with KV length 1: softmax over size-1 axis == 1, so Q/K are
// dead. out[b,n,:] = (freq[b] @ Wv.T + bv) @ Wo.T + bo, broadcast over n.
//
// Round 6: R5 structure, ONE change — compute kernels use split-K (16 lanes
// per output, all loads independent -> one HBM latency round-trip, shuffle
// reduce). R4 showed nt-stores run ~1.4 TB/s (L2 bypass hurts): keep regular
// stores in the broadcast (R5-verbatim).

#define B_   16
#define N_   4096
#define CSP  768
#define CFD  512

// Kernel 1: V[b,j] = bv[j] + dot(freq[b,:], Wv[j,:])
// grid (16, 48), block 256. 16 outputs/block; 16 lanes per output.
// Lane k of group g loads float4s {k + 16*i} of row j -> each group's 16
// lanes cover a contiguous 256 B run per i (fully coalesced), 8 independent
// loads per lane. Reduce over k via shfl_xor (stays inside the 64-lane wave).
__global__ void __launch_bounds__(256) compute_v(const float* __restrict__ freq,
                                                 const float* __restrict__ Wv,
                                                 const float* __restrict__ bv,
                                                 float* __restrict__ V) {
    const int b = blockIdx.x;
    const int t = threadIdx.x;
    const int g = t >> 4;              // output within block (0..15)
    const int k = t & 15;              // k-slice lane (0..15)
    const int j = blockIdx.y * 16 + g; // output channel (0..767)

    const float4* wr = (const float4*)(Wv + (size_t)j * CFD);
    const float4* fr = (const float4*)(freq + (size_t)b * CFD);

    float acc = 0.f;
#pragma unroll
    for (int i = 0; i < CFD / 4 / 16; ++i) {       // 8 iterations
        float4 w = wr[k + 16 * i];
        float4 f = fr[k + 16 * i];
        acc += w.x * f.x + w.y * f.y + w.z * f.z + w.w * f.w;
    }
#pragma unroll
    for (int m = 8; m >= 1; m >>= 1)
        acc += __shfl_xor(acc, m);
    if (k == 0) V[(size_t)b * CSP + j] = acc + bv[j];
}

// Kernel 2: O2[b,c] = bo[c] + dot(V[b,:], Wo[c,:])
// Same split-K layout, K=768 -> 12 independent float4 loads per lane
// (V row is 3 KB and L2-hot; load it per-lane alongside Wo).
__global__ void __launch_bounds__(256) compute_o2(const float* __restrict__ V,
                                                  const float* __restrict__ Wo,
                                                  const float* __restrict__ bo,
                                                  float* __restrict__ O2) {
    const int b = blockIdx.x;
    const int t = threadIdx.x;
    const int g = t >> 4;
    const int k = t & 15;
    const int c = blockIdx.y * 16 + g;

    const float4* wr = (const float4*)(Wo + (size_t)c * CSP);
    const float4* vr = (const float4*)(V + (size_t)b * CSP);

    float acc = 0.f;
#pragma unroll
    for (int i = 0; i < CSP / 4 / 16; ++i) {       // 12 iterations
        float4 w = wr[k + 16 * i];
        float4 v = vr[k + 16 * i];
        acc += w.x * v.x + w.y * v.y + w.z * v.z + w.w * v.w;
    }
#pragma unroll
    for (int m = 8; m >= 1; m >>= 1)
        acc += __shfl_xor(acc, m);
    if (k == 0) O2[(size_t)b * CSP + c] = acc + bo[c];
}

// Kernel 3 (R5-verbatim): streaming broadcast, out[b,n,:] = O2[b,:].
// 2048 blocks x 256 threads; block k writes the k-th contiguous 96 KB chunk
// (32 rows) as 24 contiguous 4 KB slabs. Period-3 column pattern -> 3
// pre-loaded registers cover all stores. Regular (write-back) stores.
__global__ void __launch_bounds__(256) broadcast_out(
    const float* __restrict__ O2,     // [B, CSP]
    float* __restrict__ out)          // [B, N, CSP]
{
    const int blk = blockIdx.x;       // 0..2047
    const int b   = blk >> 7;         // 128 chunks per batch
    const int y   = blk & 127;
    const int t   = threadIdx.x;

    const float4* row = (const float4*)(O2 + (size_t)b * CSP);
    float4 v[3];
#pragma unroll
    for (int j = 0; j < 3; ++j) {
        int c = t + 64 * j;            // < 384
        if (c >= 192) c -= 192;
        v[j] = row[c];
    }

    float4* dst = (float4*)(out + ((size_t)b * N_ + (size_t)y * 32) * CSP) + t;
#pragma unroll
    for (int i = 0; i < 24; ++i) {
        dst[(size_t)i * 256] = v[i % 3];
    }
}

extern "C" void kernel_launch(void* const* d_in, const int* in_sizes, int n_in,
                              void* d_out, int out_size, void* d_ws, size_t ws_size,
                              hipStream_t stream) {
    // Inputs (setup_inputs order):
    // 0: spatial_tokens (dead)  1: freq_token [B,CFD]
    // 2: Wq (dead) 3: bq (dead) 4: Wk (dead) 5: bk (dead)
    // 6: Wv [CSP,CFD] 7: bv [CSP] 8: Wo [CSP,CSP] 9: bo [CSP]
    const float* freq = (const float*)d_in[1];
    const float* Wv   = (const float*)d_in[6];
    const float* bv   = (const float*)d_in[7];
    const float* Wo   = (const float*)d_in[8];
    const float* bo   = (const float*)d_in[9];
    float* out = (float*)d_out;

    float* V  = (float*)d_ws;            // [B, CSP]
    float* O2 = V + (size_t)B_ * CSP;    // [B, CSP]

    compute_v <<<dim3(B_, CSP / 16), 256, 0, stream>>>(freq, Wv, bv, V);
    compute_o2<<<dim3(B_, CSP / 16), 256, 0, stream>>>(V, Wo, bo, O2);
    broadcast_out<<<dim3(2048), 256, 0, stream>>>(O2, out);
}

// Round 7
// 314.470 us; speedup vs baseline: 1.3386x; 1.0095x over previous
//
#include <hip/hip_runtime.h>
#include <hip/hip_bf16.h>

// CrossAttention with KV length 1: softmax over size-1 axis == 1, so Q/K are
// dead. out[b,n,:] = (freq[b] @ Wv.T + bv) @ Wo.T + bo, broadcast over n.
//
// Round 7: R6 computes (split-K, verified -29us) verbatim; ONE change — the
// broadcast is restructured fill-style: 4096 blocks x 192 threads, one fixed
// float4 register per thread (col4 == t), 16 row-stores per block at 256-row
// stride. Many cheap 3-wave blocks cycle through CUs like the 6.6 TB/s
// harness fill, instead of 8 heavyweight one-shot blocks/CU.

#define B_   16
#define N_   4096
#define CSP  768
#define CFD  512

// Kernel 1: V[b,j] = bv[j] + dot(freq[b,:], Wv[j,:])
// grid (16, 48), block 256. 16 outputs/block; 16 lanes per output; split-K
// with shfl_xor reduce (all loads independent -> one latency round-trip).
__global__ void __launch_bounds__(256) compute_v(const float* __restrict__ freq,
                                                 const float* __restrict__ Wv,
                                                 const float* __restrict__ bv,
                                                 float* __restrict__ V) {
    const int b = blockIdx.x;
    const int t = threadIdx.x;
    const int g = t >> 4;              // output within block (0..15)
    const int k = t & 15;              // k-slice lane (0..15)
    const int j = blockIdx.y * 16 + g; // output channel (0..767)

    const float4* wr = (const float4*)(Wv + (size_t)j * CFD);
    const float4* fr = (const float4*)(freq + (size_t)b * CFD);

    float acc = 0.f;
#pragma unroll
    for (int i = 0; i < CFD / 4 / 16; ++i) {       // 8 iterations
        float4 w = wr[k + 16 * i];
        float4 f = fr[k + 16 * i];
        acc += w.x * f.x + w.y * f.y + w.z * f.z + w.w * f.w;
    }
#pragma unroll
    for (int m = 8; m >= 1; m >>= 1)
        acc += __shfl_xor(acc, m);
    if (k == 0) V[(size_t)b * CSP + j] = acc + bv[j];
}

// Kernel 2: O2[b,c] = bo[c] + dot(V[b,:], Wo[c,:])  — same split-K layout.
__global__ void __launch_bounds__(256) compute_o2(const float* __restrict__ V,
                                                  const float* __restrict__ Wo,
                                                  const float* __restrict__ bo,
                                                  float* __restrict__ O2) {
    const int b = blockIdx.x;
    const int t = threadIdx.x;
    const int g = t >> 4;
    const int k = t & 15;
    const int c = blockIdx.y * 16 + g;

    const float4* wr = (const float4*)(Wo + (size_t)c * CSP);
    const float4* vr = (const float4*)(V + (size_t)b * CSP);

    float acc = 0.f;
#pragma unroll
    for (int i = 0; i < CSP / 4 / 16; ++i) {       // 12 iterations
        float4 w = wr[k + 16 * i];
        float4 v = vr[k + 16 * i];
        acc += w.x * v.x + w.y * v.y + w.z * v.z + w.w * v.w;
    }
#pragma unroll
    for (int m = 8; m >= 1; m >>= 1)
        acc += __shfl_xor(acc, m);
    if (k == 0) O2[(size_t)b * CSP + c] = acc + bo[c];
}

// Kernel 3: fill-style broadcast, out[b,n,:] = O2[b,:].
// grid 4096, block 192 (3 waves). Block k: batch b = k>>8, row offset
// y0 = k&255; writes rows y0, y0+256, ..., y0+3840 (16 rows). Thread t holds
// the single float4 col t of O2[b] in one register; each iteration the block
// stores one contiguous 3 KB row (192 x 16 B), consecutive blocks cover
// consecutive rows.
__global__ void __launch_bounds__(192) broadcast_out(
    const float* __restrict__ O2,     // [B, CSP]
    float* __restrict__ out)          // [B, N, CSP]
{
    const int k  = blockIdx.x;        // 0..4095
    const int b  = k >> 8;            // 256 blocks per batch
    const int y0 = k & 255;
    const int t  = threadIdx.x;       // 0..191

    const float4 v = ((const float4*)(O2 + (size_t)b * CSP))[t];

    float4* dst = (float4*)(out + ((size_t)b * N_ + (size_t)y0) * CSP) + t;
#pragma unroll
    for (int i = 0; i < 16; ++i) {
        dst[(size_t)i * 256 * (CSP / 4)] = v;    // stride 256 rows = 768 KB
    }
}

extern "C" void kernel_launch(void* const* d_in, const int* in_sizes, int n_in,
                              void* d_out, int out_size, void* d_ws, size_t ws_size,
                              hipStream_t stream) {
    // Inputs (setup_inputs order):
    // 0: spatial_tokens (dead)  1: freq_token [B,CFD]
    // 2: Wq (dead) 3: bq (dead) 4: Wk (dead) 5: bk (dead)
    // 6: Wv [CSP,CFD] 7: bv [CSP] 8: Wo [CSP,CSP] 9: bo [CSP]
    const float* freq = (const float*)d_in[1];
    const float* Wv   = (const float*)d_in[6];
    const float* bv   = (const float*)d_in[7];
    const float* Wo   = (const float*)d_in[8];
    const float* bo   = (const float*)d_in[9];
    float* out = (float*)d_out;

    float* V  = (float*)d_ws;            // [B, CSP]
    float* O2 = V + (size_t)B_ * CSP;    // [B, CSP]

    compute_v <<<dim3(B_, CSP / 16), 256, 0, stream>>>(freq, Wv, bv, V);
    compute_o2<<<dim3(B_, CSP / 16), 256, 0, stream>>>(V, Wo, bo, O2);
    broadcast_out<<<dim3(4096), 192, 0, stream>>>(O2, out);
}